// Round 1
// baseline (410.604 us; speedup 1.0000x reference)
//
#include <hip/hip_runtime.h>
#include <math.h>

#define IMG_H 1024
#define IMG_W 1024
#define OUT_H 1025
#define OUT_W 1025
#define NIMG  16

// Map bp (double-reflect-padded) row/col index k in [0,1026] to source image index.
// bp row map: [x0, x1, x0, x1, x2, ..., x1023, x1022]
__device__ __forceinline__ int refl(int k) {
    if (k >= 2) return (k <= 1025) ? (k - 2) : 1022;
    return k; // 0->0, 1->1
}

// Compute gradient magnitude (f32, reference op order) and direction bin at
// output pixel (i,j), i,j in [0,1024].
__device__ __forceinline__ void gxybin(const float* __restrict__ img, int i, int j,
                                       float& g, int& bin) {
    int r0 = refl(i), r1 = refl(i + 1), r2 = refl(i + 2);
    int c0 = refl(j), c1 = refl(j + 1), c2 = refl(j + 2);
    const float* p0 = img + r0 * IMG_W;
    const float* p1 = img + r1 * IMG_W;
    const float* p2 = img + r2 * IMG_W;
    float v00 = p0[c0], v01 = p0[c1], v02 = p0[c2];
    float v10 = p1[c0],               v12 = p1[c2];
    float v20 = p2[c0], v21 = p2[c1], v22 = p2[c2];

    // gx: taps (0,0):-1 (0,2):+1 (1,0):-2 (1,2):+2 (2,0):-1 (2,2):+1, row-major order
    float gx = -v00;
    gx = __fadd_rn(gx, v02);
    gx = __fadd_rn(gx, -2.0f * v10);
    gx = __fadd_rn(gx, 2.0f * v12);
    gx = __fadd_rn(gx, -v20);
    gx = __fadd_rn(gx, v22);
    // gy: taps (0,0):-1 (0,1):-2 (0,2):-1 (2,0):+1 (2,1):+2 (2,2):+1
    float gy = -v00;
    gy = __fadd_rn(gy, -2.0f * v01);
    gy = __fadd_rn(gy, -v02);
    gy = __fadd_rn(gy, v20);
    gy = __fadd_rn(gy, 2.0f * v21);
    gy = __fadd_rn(gy, v22);

    g = __fsqrt_rn(__fadd_rn(__fmul_rn(gx, gx), __fmul_rn(gy, gy)));

    // theta = (atan2f(gx, gy) * (180/pi) + 90) mod 180, f32 chain; atan2 done in
    // double then rounded -> (approx) correctly-rounded f32 atan2f.
    float t = (float)atan2((double)gx, (double)gy);
    float deg = __fmul_rn(t, (float)(180.0 / M_PI));
    float th = __fadd_rn(deg, 90.0f);
    th = fmodf(th, 180.0f);
    if (th < 0.0f) th += 180.0f;

    if (th < 22.5f || th >= 157.5f)      bin = 0;
    else if (th < 67.5f)                 bin = 1;
    else if (th < 112.5f)                bin = 2;
    else                                 bin = 3;
}

__global__ __launch_bounds__(256) void canny_kernel(const float* __restrict__ images,
                                                    float* __restrict__ out) {
    long long tid = (long long)blockIdx.x * 256 + threadIdx.x;
    const long long total = (long long)NIMG * OUT_H * OUT_W;
    if (tid >= total) return;

    int n   = (int)(tid / (OUT_H * OUT_W));
    int rem = (int)(tid % (OUT_H * OUT_W));
    int i = rem / OUT_W;
    int j = rem % OUT_W;

    const float* img = images + (size_t)n * IMG_H * IMG_W;

    float gc; int bc;
    gxybin(img, i, j, gc, bc);

    // directional neighbor offsets per bin: neighbors at (i+di,j+dj) and (i-di,j-dj)
    int di, dj;
    switch (bc) {
        case 0:  di = 0; dj = 1;  break;  // horizontal
        case 1:  di = 1; dj = -1; break;  // anti-diagonal
        case 2:  di = 1; dj = 0;  break;  // vertical
        default: di = 1; dj = 1;  break;  // diagonal
    }

    float nmax = 0.0f;
    int i1 = i + di, j1 = j + dj;
    if (i1 >= 0 && i1 < OUT_H && j1 >= 0 && j1 < OUT_W) {
        float gn; int bn;
        gxybin(img, i1, j1, gn, bn);
        if (bn == bc && gn > nmax) nmax = gn;
    }
    int i2 = i - di, j2 = j - dj;
    if (i2 >= 0 && i2 < OUT_H && j2 >= 0 && j2 < OUT_W) {
        float gn; int bn;
        gxybin(img, i2, j2, gn, bn);
        if (bn == bc && gn > nmax) nmax = gn;
    }

    float e = (gc >= nmax) ? gc : 0.0f;

    float v_img  = (e >= 50.0f) ? 255.5f : 0.0f;
    float v_week = (e >= 50.0f && e < 100.0f) ? 255.0f : 0.0f;
    float v_sure = (e >= 100.0f) ? 255.0f : 0.0f;

    out[tid]             = v_img;
    out[total + tid]     = v_week;
    out[2 * total + tid] = v_sure;
}

extern "C" void kernel_launch(void* const* d_in, const int* in_sizes, int n_in,
                              void* d_out, int out_size, void* d_ws, size_t ws_size,
                              hipStream_t stream) {
    const float* images = (const float*)d_in[0];
    float* out = (float*)d_out;
    const long long total = (long long)NIMG * OUT_H * OUT_W;
    int blocks = (int)((total + 255) / 256);
    canny_kernel<<<blocks, 256, 0, stream>>>(images, out);
}

// Round 2
// 365.934 us; speedup vs baseline: 1.1221x; 1.1221x over previous
//
#include <hip/hip_runtime.h>
#include <math.h>

#define IMG_H 1024
#define IMG_W 1024
#define OUT_H 1025
#define OUT_W 1025
#define NIMG  16
#define TOTAL (NIMG * OUT_H * OUT_W)

// Map bp (double-reflect-padded) row/col index k in [0,1026] to source image index.
__device__ __forceinline__ int refl(int k) {
    if (k >= 2) return (k <= 1025) ? (k - 2) : 1022;
    return k; // 0->0, 1->1
}

// Sobel gx/gy at output pixel (i,j) — exact f32 op order of the passing r1 kernel.
__device__ __forceinline__ void sobel(const float* __restrict__ img, int i, int j,
                                      float& gx, float& gy) {
    int r0 = refl(i), r1 = refl(i + 1), r2 = refl(i + 2);
    int c0 = refl(j), c1 = refl(j + 1), c2 = refl(j + 2);
    const float* p0 = img + r0 * IMG_W;
    const float* p1 = img + r1 * IMG_W;
    const float* p2 = img + r2 * IMG_W;
    float v00 = p0[c0], v01 = p0[c1], v02 = p0[c2];
    float v10 = p1[c0],               v12 = p1[c2];
    float v20 = p2[c0], v21 = p2[c1], v22 = p2[c2];

    float t = -v00;
    t = __fadd_rn(t, v02);
    t = __fadd_rn(t, -2.0f * v10);
    t = __fadd_rn(t, 2.0f * v12);
    t = __fadd_rn(t, -v20);
    gx = __fadd_rn(t, v22);

    t = -v00;
    t = __fadd_rn(t, -2.0f * v01);
    t = __fadd_rn(t, -v02);
    t = __fadd_rn(t, v20);
    t = __fadd_rn(t, 2.0f * v21);
    gy = __fadd_rn(t, v22);
}

// Exact reference binning (double atan2 -> f32 chain). Bit-matched np in r1.
__device__ int classify_slow(float gx, float gy) {
    float t = (float)atan2((double)gx, (double)gy);
    float deg = __fmul_rn(t, (float)(180.0 / M_PI));
    float th = __fadd_rn(deg, 90.0f);
    th = fmodf(th, 180.0f);
    if (th < 0.0f) th += 180.0f;
    if (th < 22.5f || th >= 157.5f) return 0;
    if (th < 67.5f) return 1;
    if (th < 112.5f) return 2;
    return 3;
}

// Fast binning via sign + ratio comparisons with a guard band; guard-band
// pixels (~1e-4 of all) defer to the exact chain.
__device__ __forceinline__ int classify(float gx, float gy) {
    float ax = fabsf(gx), ay = fabsf(gy);
    // tan(22.5 deg) * (1 -/+ 1e-4), tan(67.5 deg) * (1 -/+ 1e-4)
    const float T22_LO = 0.414172141e0f;
    const float T22_HI = 0.414254984e0f;
    const float T67_LO = 2.413972141e0f;
    const float T67_HI = 2.414454984e0f;

    // Order matters: (0,0) must land in bin 2 (atan2(0,0)=0 -> theta=90).
    if (ax <= ay * T22_LO) return 2;                  // |gx| << |gy|: vertical
    if (ax >= ay * T67_HI) return 0;                  // |gx| >> |gy|: horizontal
    if (ax >= ay * T22_HI && ax <= ay * T67_LO) {
        // strictly inside the diagonal band: gx,gy both nonzero
        unsigned s = (__float_as_uint(gx) ^ __float_as_uint(gy)) >> 31;
        return s ? 1 : 3;                             // opposite signs -> anti-diagonal
    }
    return classify_slow(gx, gy);                     // within guard band of a boundary
}

__device__ __forceinline__ float mag(float gx, float gy) {
    return __fsqrt_rn(__fadd_rn(__fmul_rn(gx, gx), __fmul_rn(gy, gy)));
}

__global__ __launch_bounds__(256) void canny_kernel(const float* __restrict__ images,
                                                    float* __restrict__ out) {
    int tid = blockIdx.x * 256 + threadIdx.x;
    if (tid >= TOTAL) return;

    int n   = tid / (OUT_H * OUT_W);
    int rem = tid % (OUT_H * OUT_W);
    int i = rem / OUT_W;
    int j = rem % OUT_W;

    const float* img = images + (size_t)n * IMG_H * IMG_W;

    float gxc, gyc;
    sobel(img, i, j, gxc, gyc);
    float gc = mag(gxc, gyc);
    int bc = classify(gxc, gyc);

    int di, dj;
    switch (bc) {
        case 0:  di = 0; dj = 1;  break;  // horizontal
        case 1:  di = 1; dj = -1; break;  // anti-diagonal
        case 2:  di = 1; dj = 0;  break;  // vertical
        default: di = 1; dj = 1;  break;  // diagonal
    }

    float nmax = 0.0f;
    int i1 = i + di, j1 = j + dj;
    if (i1 >= 0 && i1 < OUT_H && j1 >= 0 && j1 < OUT_W) {
        float gxn, gyn;
        sobel(img, i1, j1, gxn, gyn);
        if (classify(gxn, gyn) == bc) {
            float gn = mag(gxn, gyn);
            if (gn > nmax) nmax = gn;
        }
    }
    int i2 = i - di, j2 = j - dj;
    if (i2 >= 0 && i2 < OUT_H && j2 >= 0 && j2 < OUT_W) {
        float gxn, gyn;
        sobel(img, i2, j2, gxn, gyn);
        if (classify(gxn, gyn) == bc) {
            float gn = mag(gxn, gyn);
            if (gn > nmax) nmax = gn;
        }
    }

    float e = (gc >= nmax) ? gc : 0.0f;

    out[tid]             = (e >= 50.0f) ? 255.5f : 0.0f;
    out[TOTAL + tid]     = (e >= 50.0f && e < 100.0f) ? 255.0f : 0.0f;
    out[2 * TOTAL + tid] = (e >= 100.0f) ? 255.0f : 0.0f;
}

extern "C" void kernel_launch(void* const* d_in, const int* in_sizes, int n_in,
                              void* d_out, int out_size, void* d_ws, size_t ws_size,
                              hipStream_t stream) {
    const float* images = (const float*)d_in[0];
    float* out = (float*)d_out;
    int blocks = (TOTAL + 255) / 256;
    canny_kernel<<<blocks, 256, 0, stream>>>(images, out);
}

// Round 3
// 315.463 us; speedup vs baseline: 1.3016x; 1.1600x over previous
//
#include <hip/hip_runtime.h>
#include <math.h>

#define IMG_H 1024
#define IMG_W 1024
#define OUT_H 1025
#define OUT_W 1025
#define NIMG  16
#define TOTAL (NIMG * OUT_H * OUT_W)

#define TILE_W 64
#define TILE_H 16
#define HALO_W (TILE_W + 2)   // 66
#define HALO_H (TILE_H + 2)   // 18
#define NHALO  (HALO_W * HALO_H)  // 1188

// Map bp (double-reflect-padded) row/col index k in [0,1026] to source image index.
__device__ __forceinline__ int refl(int k) {
    if (k >= 2) return (k <= 1025) ? (k - 2) : 1022;
    return k; // 0->0, 1->1
}

// Sobel gx/gy at output pixel (i,j) — exact f32 op order of the passing r1/r2 kernel.
__device__ __forceinline__ void sobel(const float* __restrict__ img, int i, int j,
                                      float& gx, float& gy) {
    int r0 = refl(i), r1 = refl(i + 1), r2 = refl(i + 2);
    int c0 = refl(j), c1 = refl(j + 1), c2 = refl(j + 2);
    const float* p0 = img + r0 * IMG_W;
    const float* p1 = img + r1 * IMG_W;
    const float* p2 = img + r2 * IMG_W;
    float v00 = p0[c0], v01 = p0[c1], v02 = p0[c2];
    float v10 = p1[c0],               v12 = p1[c2];
    float v20 = p2[c0], v21 = p2[c1], v22 = p2[c2];

    float t = -v00;
    t = __fadd_rn(t, v02);
    t = __fadd_rn(t, -2.0f * v10);
    t = __fadd_rn(t, 2.0f * v12);
    t = __fadd_rn(t, -v20);
    gx = __fadd_rn(t, v22);

    t = -v00;
    t = __fadd_rn(t, -2.0f * v01);
    t = __fadd_rn(t, -v02);
    t = __fadd_rn(t, v20);
    t = __fadd_rn(t, 2.0f * v21);
    gy = __fadd_rn(t, v22);
}

// Exact reference binning (double atan2 -> f32 chain). Bit-matched np in r1.
__device__ int classify_slow(float gx, float gy) {
    float t = (float)atan2((double)gx, (double)gy);
    float deg = __fmul_rn(t, (float)(180.0 / M_PI));
    float th = __fadd_rn(deg, 90.0f);
    th = fmodf(th, 180.0f);
    if (th < 0.0f) th += 180.0f;
    if (th < 22.5f || th >= 157.5f) return 0;
    if (th < 67.5f) return 1;
    if (th < 112.5f) return 2;
    return 3;
}

// Fast binning via sign + ratio comparisons with a guard band; guard-band
// pixels (~1e-4 of all) defer to the exact chain. Bit-matched np in r2.
__device__ __forceinline__ int classify(float gx, float gy) {
    float ax = fabsf(gx), ay = fabsf(gy);
    const float T22_LO = 0.414172141e0f;
    const float T22_HI = 0.414254984e0f;
    const float T67_LO = 2.413972141e0f;
    const float T67_HI = 2.414454984e0f;

    if (ax <= ay * T22_LO) return 2;                  // (0,0) lands here: bin 2
    if (ax >= ay * T67_HI) return 0;
    if (ax >= ay * T22_HI && ax <= ay * T67_LO) {
        unsigned s = (__float_as_uint(gx) ^ __float_as_uint(gy)) >> 31;
        return s ? 1 : 3;
    }
    return classify_slow(gx, gy);
}

__device__ __forceinline__ float mag(float gx, float gy) {
    return __fsqrt_rn(__fadd_rn(__fmul_rn(gx, gx), __fmul_rn(gy, gy)));
}

__global__ __launch_bounds__(256) void canny_kernel(const float* __restrict__ images,
                                                    float* __restrict__ out) {
    __shared__ float         g_s[NHALO];
    __shared__ unsigned char b_s[NHALO];

    const int tile_ox = blockIdx.x * TILE_W;
    const int tile_oy = blockIdx.y * TILE_H;
    const int n       = blockIdx.z;
    const float* img = images + (size_t)n * IMG_H * IMG_W;
    const int t = threadIdx.x;

    // Phase 1: g + bin for the 66x18 halo (once per block).
    for (int idx = t; idx < NHALO; idx += 256) {
        int hy = idx / HALO_W;
        int hx = idx - hy * HALO_W;
        int oy = tile_oy + hy - 1;
        int ox = tile_ox + hx - 1;
        float g = -1.0f;
        int   b = 255;
        if (oy >= 0 && oy < OUT_H && ox >= 0 && ox < OUT_W) {
            float gx, gy;
            sobel(img, oy, ox, gx, gy);
            g = mag(gx, gy);
            b = classify(gx, gy);
        }
        g_s[idx] = g;
        b_s[idx] = (unsigned char)b;
    }
    __syncthreads();

    // Phase 2: NMS + thresholds from LDS.
    const int col = t & (TILE_W - 1);
    const int row0 = t >> 6;          // 0..3
    const int ox = tile_ox + col;
    if (ox >= OUT_W) return;

    #pragma unroll
    for (int q = 0; q < 4; q++) {
        int r = row0 + q * 4;         // 0..15
        int oy = tile_oy + r;
        if (oy >= OUT_H) continue;

        int hc = (r + 1) * HALO_W + (col + 1);
        float gc = g_s[hc];
        int   bc = b_s[hc];

        int doff;                     // LDS offset of the +direction neighbor
        switch (bc) {
            case 0:  doff = 1;            break;  // horizontal  (0,+1)
            case 1:  doff = HALO_W - 1;   break;  // anti-diag   (+1,-1)
            case 2:  doff = HALO_W;       break;  // vertical    (+1,0)
            default: doff = HALO_W + 1;   break;  // diagonal    (+1,+1)
        }

        float nmax = 0.0f;
        float g1 = g_s[hc + doff];
        if (b_s[hc + doff] == bc && g1 > nmax) nmax = g1;
        float g2 = g_s[hc - doff];
        if (b_s[hc - doff] == bc && g2 > nmax) nmax = g2;

        float e = (gc >= nmax) ? gc : 0.0f;

        size_t o = (size_t)(n * OUT_H + oy) * OUT_W + ox;
        out[o]                       = (e >= 50.0f) ? 255.5f : 0.0f;
        out[(size_t)TOTAL + o]       = (e >= 50.0f && e < 100.0f) ? 255.0f : 0.0f;
        out[(size_t)(2 * TOTAL) + o] = (e >= 100.0f) ? 255.0f : 0.0f;
    }
}

extern "C" void kernel_launch(void* const* d_in, const int* in_sizes, int n_in,
                              void* d_out, int out_size, void* d_ws, size_t ws_size,
                              hipStream_t stream) {
    const float* images = (const float*)d_in[0];
    float* out = (float*)d_out;
    dim3 grid((OUT_W + TILE_W - 1) / TILE_W,   // 17
              (OUT_H + TILE_H - 1) / TILE_H,   // 65
              NIMG);                            // 16
    canny_kernel<<<grid, 256, 0, stream>>>(images, out);
}

// Round 4
// 297.760 us; speedup vs baseline: 1.3790x; 1.0595x over previous
//
#include <hip/hip_runtime.h>
#include <math.h>

#define IMG_H 1024
#define IMG_W 1024
#define OUT_H 1025
#define OUT_W 1025
#define NIMG  16
#define TOTAL (NIMG * OUT_H * OUT_W)

#define TILE_W 64
#define TILE_H 16
#define HALO_W 68                 // ox in [tile_ox-2, tile_ox+65]
#define HALO_H 18                 // oy in [tile_oy-1, tile_oy+16]
#define NQX    17                 // 68/4 x-quads per halo row
#define NQUAD  (HALO_H * NQX)     // 306
#define NTHREADS 320

// Map bp (double-reflect-padded) row/col index k in [0,1026] to source image index.
__device__ __forceinline__ int refl(int k) {
    if (k >= 2) return (k <= 1025) ? (k - 2) : 1022;
    return k;
}

// Generic sobel at output (i,j) — exact f32 op order (bit-matched np in r1-r3).
__device__ __forceinline__ void sobel_generic(const float* __restrict__ img, int i, int j,
                                              float& gx, float& gy) {
    int r0 = refl(i), r1 = refl(i + 1), r2 = refl(i + 2);
    int c0 = refl(j), c1 = refl(j + 1), c2 = refl(j + 2);
    const float* p0 = img + r0 * IMG_W;
    const float* p1 = img + r1 * IMG_W;
    const float* p2 = img + r2 * IMG_W;
    float v00 = p0[c0], v01 = p0[c1], v02 = p0[c2];
    float v10 = p1[c0],               v12 = p1[c2];
    float v20 = p2[c0], v21 = p2[c1], v22 = p2[c2];

    float t = -v00;
    t = __fadd_rn(t, v02);
    t = __fadd_rn(t, -2.0f * v10);
    t = __fadd_rn(t, 2.0f * v12);
    t = __fadd_rn(t, -v20);
    gx = __fadd_rn(t, v22);

    t = -v00;
    t = __fadd_rn(t, -2.0f * v01);
    t = __fadd_rn(t, -v02);
    t = __fadd_rn(t, v20);
    t = __fadd_rn(t, 2.0f * v21);
    gy = __fadd_rn(t, v22);
}

// Exact reference binning (double atan2 -> f32 chain). Bit-matched np in r1.
__device__ int classify_slow(float gx, float gy) {
    float t = (float)atan2((double)gx, (double)gy);
    float deg = __fmul_rn(t, (float)(180.0 / M_PI));
    float th = __fadd_rn(deg, 90.0f);
    th = fmodf(th, 180.0f);
    if (th < 0.0f) th += 180.0f;
    if (th < 22.5f || th >= 157.5f) return 0;
    if (th < 67.5f) return 1;
    if (th < 112.5f) return 2;
    return 3;
}

// Fast binning: sign + ratio comparisons with guard band (bit-matched np in r2/r3).
__device__ __forceinline__ int classify(float gx, float gy) {
    float ax = fabsf(gx), ay = fabsf(gy);
    const float T22_LO = 0.414172141e0f;
    const float T22_HI = 0.414254984e0f;
    const float T67_LO = 2.413972141e0f;
    const float T67_HI = 2.414454984e0f;

    if (ax <= ay * T22_LO) return 2;                  // (0,0) lands here: bin 2
    if (ax >= ay * T67_HI) return 0;
    if (ax >= ay * T22_HI && ax <= ay * T67_LO) {
        unsigned s = (__float_as_uint(gx) ^ __float_as_uint(gy)) >> 31;
        return s ? 1 : 3;
    }
    return classify_slow(gx, gy);
}

__device__ __forceinline__ float mag(float gx, float gy) {
    return __fsqrt_rn(__fadd_rn(__fmul_rn(gx, gx), __fmul_rn(gy, gy)));
}

__device__ __forceinline__ void load6(const float* __restrict__ p, float v[6]) {
    float4 a = *(const float4*)p;        // 16B aligned: col base ≡ 0 (mod 4)
    float2 b = *(const float2*)(p + 4);
    v[0] = a.x; v[1] = a.y; v[2] = a.z; v[3] = a.w; v[4] = b.x; v[5] = b.y;
}

__global__ __launch_bounds__(NTHREADS) void canny_kernel(const float* __restrict__ images,
                                                         float* __restrict__ out) {
    __shared__ float    g_s[HALO_H * HALO_W];
    __shared__ unsigned b_u[HALO_H * NQX];

    const int tile_ox = blockIdx.x * TILE_W;
    const int tile_oy = blockIdx.y * TILE_H;
    const int n       = blockIdx.z;
    const float* img = images + (size_t)n * IMG_H * IMG_W;
    const int t = threadIdx.x;

    // ---- Phase 1: g + bin for the 18x68 halo, one x-quad per thread ----
    if (t < NQUAD) {
        int hy  = t / NQX;
        int qx  = t - hy * NQX;
        int oy  = tile_oy + hy - 1;
        int ox0 = tile_ox + qx * 4 - 2;   // ≡ 2 (mod 4)

        float    gq[4];
        unsigned bq[4];

        if (oy >= 2 && oy <= 1023 && ox0 >= 2 && ox0 <= 1020) {
            // Interior fast path: rows oy-2..oy, cols ox0-2..ox0+3, no reflection.
            const float* r0p = img + (oy - 2) * IMG_W + (ox0 - 2);
            float R0[6], R1[6], R2[6];
            load6(r0p, R0);
            load6(r0p + IMG_W, R1);
            load6(r0p + 2 * IMG_W, R2);
            #pragma unroll
            for (int p = 0; p < 4; p++) {
                float v00 = R0[p], v01 = R0[p + 1], v02 = R0[p + 2];
                float v10 = R1[p],                  v12 = R1[p + 2];
                float v20 = R2[p], v21 = R2[p + 1], v22 = R2[p + 2];

                float s = -v00;
                s = __fadd_rn(s, v02);
                s = __fadd_rn(s, -2.0f * v10);
                s = __fadd_rn(s, 2.0f * v12);
                s = __fadd_rn(s, -v20);
                float gx = __fadd_rn(s, v22);

                s = -v00;
                s = __fadd_rn(s, -2.0f * v01);
                s = __fadd_rn(s, -v02);
                s = __fadd_rn(s, v20);
                s = __fadd_rn(s, 2.0f * v21);
                float gy = __fadd_rn(s, v22);

                gq[p] = mag(gx, gy);
                bq[p] = (unsigned)classify(gx, gy);
            }
        } else {
            // Boundary quad: per-pixel generic (reflection + bounds).
            #pragma unroll
            for (int p = 0; p < 4; p++) {
                int ox = ox0 + p;
                float g = -1.0f;
                unsigned b = 255u;
                if (oy >= 0 && oy < OUT_H && ox >= 0 && ox < OUT_W) {
                    float gx, gy;
                    sobel_generic(img, oy, ox, gx, gy);
                    g = mag(gx, gy);
                    b = (unsigned)classify(gx, gy);
                }
                gq[p] = g;
                bq[p] = b;
            }
        }

        int ldoff = hy * HALO_W + qx * 4;            // dword index, multiple of 4
        *(float4*)&g_s[ldoff] = make_float4(gq[0], gq[1], gq[2], gq[3]);
        b_u[hy * NQX + qx] = bq[0] | (bq[1] << 8) | (bq[2] << 16) | (bq[3] << 24);
    }
    __syncthreads();

    // ---- Phase 2: NMS + thresholds from LDS ----
    const unsigned char* b_s = (const unsigned char*)b_u;
    #pragma unroll
    for (int q = 0; q < 4; q++) {
        int p = t + NTHREADS * q;
        if (p >= TILE_W * TILE_H) break;             // only q=3 is partial
        int r = p >> 6, c = p & 63;
        int oy = tile_oy + r, ox = tile_ox + c;
        if (oy >= OUT_H || ox >= OUT_W) continue;

        int hc = (r + 1) * HALO_W + (c + 2);
        float gc = g_s[hc];
        int   bc = b_s[hc];

        int doff = (bc == 0) ? 1
                 : (bc == 1) ? (HALO_W - 1)
                 : (bc == 2) ? HALO_W
                 :             (HALO_W + 1);

        float nmax = 0.0f;
        float g1 = g_s[hc + doff];
        if (b_s[hc + doff] == bc && g1 > nmax) nmax = g1;
        float g2 = g_s[hc - doff];
        if (b_s[hc - doff] == bc && g2 > nmax) nmax = g2;

        float e = (gc >= nmax) ? gc : 0.0f;

        size_t o = (size_t)(n * OUT_H + oy) * OUT_W + ox;
        out[o]                       = (e >= 50.0f) ? 255.5f : 0.0f;
        out[(size_t)TOTAL + o]       = (e >= 50.0f && e < 100.0f) ? 255.0f : 0.0f;
        out[(size_t)(2 * TOTAL) + o] = (e >= 100.0f) ? 255.0f : 0.0f;
    }
}

extern "C" void kernel_launch(void* const* d_in, const int* in_sizes, int n_in,
                              void* d_out, int out_size, void* d_ws, size_t ws_size,
                              hipStream_t stream) {
    const float* images = (const float*)d_in[0];
    float* out = (float*)d_out;
    dim3 grid((OUT_W + TILE_W - 1) / TILE_W,   // 17
              (OUT_H + TILE_H - 1) / TILE_H,   // 65
              NIMG);                            // 16
    canny_kernel<<<grid, NTHREADS, 0, stream>>>(images, out);
}